// Round 13
// baseline (157.677 us; speedup 1.0000x reference)
//
#include <hip/hip_runtime.h>
#include <math.h>

#define NB 4
#define NV 512
#define NF 64
#define NT 16
#define NE 16384

// ---------------- workspace layout (float offsets) ----------------
#define TX1_OFF    2097152u    // 2097152  (also ST until k_prop1)
#define SIGT_OFF   4194304u    // 2097152
#define ST_OFF     TX1_OFF
#define BST_OFF    8388608u    // bs transposed 262144
#define ET_OFF     8650752u    // (B,16,16) 1024
#define PART_OFF   8651776u    // lhs1 partials 4*8*1024 = 32768
#define RHST_OFF   8684544u    // rhs_t (B,N,T) 32768
#define LHSS_OFF   8717312u    // lhs_s (B,N,T) 32768
#define RHSSN_OFF  8750080u    // rhs_s stored (B,N,T) 32768
#define DIAGS_OFF  8782848u    // (B,N) 2048
#define CSRW_OFF   8850432u    // 16384
#define WTT_OFF    8866816u    // 12288
#define WRT_OFF    8879104u    // 4096
#define RHS3_OFF   8883712u    // rhs3 (B,N,T) 32768
#define EW1_OFF    8916480u    // (B,16) 64
#define MPART_OFF  8916544u    // M partials 4*8*1024 = 32768
#define WCT_OFF    8949312u    // WcT [g][3][64] 12288
#define FEND       8961600u    // floats; ints live after this

// ============ merged prep: hist + bsT + WtT/WrT + WcT + lhs1 partials + rhs/rhs3 ============
__global__ void k_prep(const int* __restrict__ ei, int* __restrict__ counts,
                       const float* __restrict__ Wt, const float* __restrict__ Wr,
                       const float* __restrict__ Wc, const float* __restrict__ bs,
                       float* __restrict__ WtT, float* __restrict__ WrT,
                       float* __restrict__ WcT, float* __restrict__ bsT,
                       const float* __restrict__ X, const float* __restrict__ U1,
                       const float* __restrict__ U3, const float* __restrict__ Ws3,
                       float* __restrict__ part, float* __restrict__ rhs,
                       float* __restrict__ rhs3) {
    __shared__ int h[512];
    __shared__ float tile[64][65];
    int bid = blockIdx.x, tid = threadIdx.x;
    if (bid < 64) {
        int c = bid;
        h[tid] = 0; h[tid + 256] = 0;
        __syncthreads();
        atomicAdd(&h[ei[c * 256 + tid]], 1);
        __syncthreads();
        counts[c * 512 + tid] = h[tid];
        counts[c * 512 + tid + 256] = h[tid + 256];
    } else if (bid < 128) {
        int tb = bid - 64;
        int r0 = (tb >> 3) * 64, c0 = (tb & 7) * 64;
        int c = tid & 63, rq = tid >> 6;
        for (int k = 0; k < 16; ++k) {
            int r = rq * 16 + k;
            tile[r][c] = bs[(r0 + r) * 512 + c0 + c];
        }
        __syncthreads();
        int r2 = tid & 63;
        for (int k = 0; k < 16; ++k) {
            int c2 = rq * 16 + k;
            bsT[(size_t)(c0 + c2) * 512 + r0 + r2] = tile[r2][c2];
        }
    } else if (bid < 192) {
        int idx = (bid - 128) * 256 + tid;
        if (idx < 12288) {
            int o = idx & 63, gd = idx >> 6;      // gd = g*3+dt
            int g = gd / 3, dt = gd - g * 3;
            WtT[idx] = Wt[(o * 64 + g) * 3 + dt];
        } else {
            int i2 = idx - 12288;
            int o = i2 & 63, f = i2 >> 6;
            WrT[i2] = Wr[o * 64 + f];
        }
    } else if (bid < 240) {
        int idx = (bid - 192) * 256 + tid;        // 0..12287
        int g = idx / 192, rem = idx - g * 192;
        int k = rem >> 6, f = rem & 63;
        WcT[idx] = Wc[k * 4096 + f * 64 + g];
    } else {
        int sub = bid - 240;
        if (sub < 32) {
            int b = sub >> 3, g = sub & 7;
            float acc[4] = {0.f, 0.f, 0.f, 0.f};
            const float* Xb = X + (size_t)b * NV * 1024;
            int n0 = g * 64;
            for (int nn = 0; nn < 64; ++nn) {
                int n = n0 + nn;
                float u = U1[n];
                const float* xp = Xb + (size_t)n * 1024;
#pragma unroll
                for (int k = 0; k < 4; ++k) acc[k] += xp[tid + 256 * k] * u;
            }
#pragma unroll
            for (int k = 0; k < 4; ++k) part[(size_t)(b * 8 + g) * 1024 + tid + 256 * k] = acc[k];
        } else {
            int gid = (sub - 32) * 256 + tid;
            int t = gid & 15;
            const float* xp = X + ((size_t)(gid >> 4)) * 1024 + t;
            float a = 0.f, a3 = 0.f;
#pragma unroll
            for (int f = 0; f < 64; ++f) {
                float v = xp[f * 16];
                a += U3[f] * v;
                a3 += Ws3[f] * v;
            }
            rhs[gid] = a;
            rhs3[gid] = a3;
        }
    }
}

// ============ fused: scan+CSR fill (blocks 0..63) + M partials (blocks 64..95) ============
__global__ __launch_bounds__(512) void k_graph(const int* __restrict__ ei,
                                               const int* __restrict__ counts,
                                               int* __restrict__ row_start,
                                               int* __restrict__ csr_col,
                                               float* __restrict__ csr_w,
                                               const float* __restrict__ rhs_g,
                                               const float* __restrict__ U2,
                                               float* __restrict__ Mpart) {
    __shared__ int sc[512];
    __shared__ int base_l[512];
    __shared__ float dis_l[512];
    __shared__ int rs_l[512];
    __shared__ int rowL[256];
    __shared__ float rhsL[1024];
    int bid = blockIdx.x, tid = threadIdx.x;
    if (bid < 64) {
        int c = bid;
        int r = tid;
        int sum = 0, base = 0;
        for (int cc = 0; cc < 64; ++cc) {
            if (cc == c) base = sum;
            sum += counts[cc * 512 + r];
        }
        base_l[r] = base;
        dis_l[r] = sum > 0 ? 1.0f / sqrtf((float)sum) : 0.0f;
        sc[r] = sum;
        __syncthreads();
        for (int off = 1; off < 512; off <<= 1) {
            int v = sc[r];
            int add = (r >= off) ? sc[r - off] : 0;
            __syncthreads();
            sc[r] = v + add;
            __syncthreads();
        }
        rs_l[r] = sc[r] - sum;          // exclusive row start
        if (c == 0) {
            row_start[r] = sc[r] - sum;
            if (r == 511) row_start[512] = sc[r];
        }
        if (tid < 256) rowL[tid] = ei[c * 256 + tid];
        __syncthreads();
        if (tid < 256) {
            int rr = rowL[tid];
            int col = ei[NE + c * 256 + tid];
            int rank = 0;
            for (int j = 0; j < tid; ++j)
                if (rowL[j] == rr) rank++;
            int pos = rs_l[rr] + base_l[rr] + rank;
            csr_col[pos] = col;
            csr_w[pos] = -dis_l[rr] * dis_l[col];
        }
    } else {
        int sub = bid - 64;             // 0..31
        int b = sub >> 3, g = sub & 7;
        rhsL[tid] = rhs_g[(size_t)b * 8192 + g * 1024 + tid];
        rhsL[tid + 512] = rhs_g[(size_t)b * 8192 + g * 1024 + tid + 512];
        __syncthreads();
        float acc[2] = {0.f, 0.f};
        int fA[2], tA[2];
#pragma unroll
        for (int k = 0; k < 2; ++k) { int idx = tid + 512 * k; fA[k] = idx >> 4; tA[k] = idx & 15; }
        int n0 = g * 64;
        for (int nn = 0; nn < 64; ++nn) {
#pragma unroll
            for (int k = 0; k < 2; ++k)
                acc[k] += U2[fA[k] * 512 + n0 + nn] * rhsL[nn * 16 + tA[k]];
        }
#pragma unroll
        for (int k = 0; k < 2; ++k) Mpart[(size_t)(b * 8 + g) * 1024 + tid + 512 * k] = acc[k];
    }
}

__global__ void k_temporal(const float* __restrict__ part, const float* __restrict__ Mpart,
                           const float* __restrict__ be,
                           const float* __restrict__ Ve, const float* __restrict__ Ws1,
                           float* __restrict__ Et, float* __restrict__ ew1) {
    __shared__ float lhs1[1024];
    __shared__ float M[1024];
    __shared__ float Esig[256];
    __shared__ float Et0[256];
    __shared__ float red[32];
    __shared__ float EtL[256];
    int b = blockIdx.x, tid = threadIdx.x;
#pragma unroll
    for (int k = 0; k < 4; ++k) {
        int idx = tid + 256 * k;
        float s = 0.f, m = 0.f;
        for (int g = 0; g < 8; ++g) {
            s += part[(size_t)(b * 8 + g) * 1024 + idx];
            m += Mpart[(size_t)(b * 8 + g) * 1024 + idx];
        }
        lhs1[idx] = s;
        M[idx] = m;
    }
    __syncthreads();
    {
        int t1 = tid >> 4, t2 = tid & 15;
        float s = 0.f;
        for (int f = 0; f < 64; ++f) s += lhs1[f * 16 + t1] * M[f * 16 + t2];
        s += be[t1 * 16 + t2];
        Esig[tid] = 1.f / (1.f + expf(-s));
    }
    __syncthreads();
    {
        int t1 = tid >> 4, t2 = tid & 15;
        float s = 0.f;
        for (int k = 0; k < 16; ++k) s += Ve[t1 * 16 + k] * Esig[k * 16 + t2];
        Et0[tid] = s;
    }
    __syncthreads();
    if (tid < 16) {
        float m = -1e30f;
        for (int k = 0; k < 16; ++k) m = fmaxf(m, Et0[k * 16 + tid]);
        float s = 0.f;
        for (int k = 0; k < 16; ++k) s += expf(Et0[k * 16 + tid] - m);
        red[tid] = m; red[16 + tid] = 1.f / s;
    }
    __syncthreads();
    {
        int t2 = tid & 15;
        float etv = expf(Et0[tid] - red[t2]) * red[16 + t2];
        Et[b * 256 + tid] = etv;
        EtL[tid] = etv;
    }
    __syncthreads();
    if (tid < 16) {
        float s = 0.f;
        for (int t = 0; t < 16; ++t) s += EtL[tid * 16 + t] * Ws1[t];
        ew1[b * 16 + tid] = s;     // ew1[tp] = sum_t Et[tp][t]*Ws1[t]
    }
}

// ============ spatial attention lhs/rhs directly from X (Xt eliminated) ============
__global__ __launch_bounds__(256) void k_spat2(const float* __restrict__ X,
                                               const float* __restrict__ ew1,
                                               const float* __restrict__ rhs3,
                                               const float* __restrict__ Et,
                                               const float* __restrict__ Ws2,
                                               float* __restrict__ lhs_s,
                                               float* __restrict__ rhs_sn) {
    int wv = threadIdx.x >> 6, lane = threadIdx.x & 63;
    int bn = blockIdx.x * 4 + wv;
    int b = bn >> 9;
    const float4* xp = (const float4*)(X + (size_t)bn * 1024 + lane * 16);
    float4 x0 = xp[0], x1 = xp[1], x2 = xp[2], x3 = xp[3];
    const float* e1 = ew1 + b * 16;
    float l1 = x0.x * e1[0] + x0.y * e1[1] + x0.z * e1[2] + x0.w * e1[3]
             + x1.x * e1[4] + x1.y * e1[5] + x1.z * e1[6] + x1.w * e1[7]
             + x2.x * e1[8] + x2.y * e1[9] + x2.z * e1[10] + x2.w * e1[11]
             + x3.x * e1[12] + x3.y * e1[13] + x3.z * e1[14] + x3.w * e1[15];
    const float4* wp = (const float4*)(Ws2 + lane * 16);
    float4 w0 = wp[0], w1 = wp[1], w2 = wp[2], w3 = wp[3];
    float p[16] = {l1 * w0.x, l1 * w0.y, l1 * w0.z, l1 * w0.w,
                   l1 * w1.x, l1 * w1.y, l1 * w1.z, l1 * w1.w,
                   l1 * w2.x, l1 * w2.y, l1 * w2.z, l1 * w2.w,
                   l1 * w3.x, l1 * w3.y, l1 * w3.z, l1 * w3.w};
#pragma unroll
    for (int off = 32; off; off >>= 1) {
#pragma unroll
        for (int k = 0; k < 16; ++k) p[k] += __shfl_xor(p[k], off);
    }
    if (lane == 0) {
        float4* lp = (float4*)(lhs_s + (size_t)bn * 16);
        lp[0] = make_float4(p[0], p[1], p[2], p[3]);
        lp[1] = make_float4(p[4], p[5], p[6], p[7]);
        lp[2] = make_float4(p[8], p[9], p[10], p[11]);
        lp[3] = make_float4(p[12], p[13], p[14], p[15]);
    }
    if (lane < 16) {
        const float* r3 = rhs3 + (size_t)bn * 16;
        const float* Eb = Et + b * 256;
        float s = 0.f;
#pragma unroll
        for (int tp = 0; tp < 16; ++tp) s += r3[tp] * Eb[tp * 16 + lane];
        rhs_sn[(size_t)bn * 16 + lane] = s;
    }
}

// grid: B*N*N/256 = 4096 blocks (b = gid>>18)
__global__ void k_sigT(const float* __restrict__ lhs_s, const float* __restrict__ rhs_sn,
                       const float* __restrict__ bsT, float* __restrict__ sigT) {
    int gid = blockIdx.x * 256 + threadIdx.x;
    int k = gid & 511, j = (gid >> 9) & 511, b = gid >> 18;
    const float4* lp = (const float4*)(lhs_s + (size_t)(b * 512 + k) * 16);
    const float4* rp = (const float4*)(rhs_sn + (size_t)(b * 512 + j) * 16);
    float s = 0.f;
#pragma unroll
    for (int q = 0; q < 4; ++q) {
        float4 a = lp[q], c = rp[q];
        s += a.x * c.x + a.y * c.y + a.z * c.z + a.w * c.w;
    }
    s += bsT[(size_t)j * 512 + k];
    sigT[gid] = 1.f / (1.f + expf(-s));
}

// S0T[b][j][i] = sum_k sigT[b][j][k] * Vs[i][k]
__global__ __launch_bounds__(256) void k_gemm_s(const float* __restrict__ sigT,
                                                const float* __restrict__ Vs,
                                                float* __restrict__ S0T) {
    __shared__ float As[32 * 68];
    __shared__ float Bs[32 * 68];
    int bI = blockIdx.x, bJ = blockIdx.y, b = blockIdx.z;
    int tid = threadIdx.x, tx = tid & 15, ty = tid >> 4;
    float acc[4][4] = {};
    const float* Ab = sigT + ((size_t)b * 512 + bJ * 64) * 512;
    const float* Bb = Vs + (size_t)bI * 64 * 512;
    for (int k0 = 0; k0 < 512; k0 += 32) {
#pragma unroll
        for (int p = 0; p < 2; ++p) {
            int idx = tid + 256 * p;
            int row = idx >> 3, kk = (idx & 7) * 4;
            float4 a = *(const float4*)(Ab + (size_t)row * 512 + k0 + kk);
            As[(kk + 0) * 68 + row] = a.x; As[(kk + 1) * 68 + row] = a.y;
            As[(kk + 2) * 68 + row] = a.z; As[(kk + 3) * 68 + row] = a.w;
            float4 v = *(const float4*)(Bb + (size_t)row * 512 + k0 + kk);
            Bs[(kk + 0) * 68 + row] = v.x; Bs[(kk + 1) * 68 + row] = v.y;
            Bs[(kk + 2) * 68 + row] = v.z; Bs[(kk + 3) * 68 + row] = v.w;
        }
        __syncthreads();
#pragma unroll
        for (int kk = 0; kk < 32; ++kk) {
            float4 a = *(const float4*)(As + kk * 68 + ty * 4);
            float4 bv = *(const float4*)(Bs + kk * 68 + tx * 4);
            acc[0][0] += a.x * bv.x; acc[0][1] += a.x * bv.y; acc[0][2] += a.x * bv.z; acc[0][3] += a.x * bv.w;
            acc[1][0] += a.y * bv.x; acc[1][1] += a.y * bv.y; acc[1][2] += a.y * bv.z; acc[1][3] += a.y * bv.w;
            acc[2][0] += a.z * bv.x; acc[2][1] += a.z * bv.y; acc[2][2] += a.z * bv.z; acc[2][3] += a.z * bv.w;
            acc[3][0] += a.w * bv.x; acc[3][1] += a.w * bv.y; acc[3][2] += a.w * bv.z; acc[3][3] += a.w * bv.w;
        }
        __syncthreads();
    }
    float* Cb = S0T + ((size_t)b * 512 + bJ * 64) * 512 + bI * 64;
#pragma unroll
    for (int y = 0; y < 4; ++y) {
        int j = ty * 4 + y;
        *(float4*)(Cb + (size_t)j * 512 + tx * 4) =
            make_float4(acc[y][0], acc[y][1], acc[y][2], acc[y][3]);
    }
}

// softmax over i (contiguous) in-place; extract diagonal
__global__ void k_softmax_s(float* __restrict__ ST, float* __restrict__ diagS) {
    __shared__ float red[4];
    int bj = blockIdx.x;
    int b = bj >> 9, j = bj & 511;
    float* row = ST + (size_t)bj * 512;
    int tid = threadIdx.x;
    float v0 = row[tid], v1 = row[tid + 256];
    float m = fmaxf(v0, v1);
    for (int off = 32; off; off >>= 1) m = fmaxf(m, __shfl_xor(m, off));
    if ((tid & 63) == 0) red[tid >> 6] = m;
    __syncthreads();
    m = fmaxf(fmaxf(red[0], red[1]), fmaxf(red[2], red[3]));
    __syncthreads();
    float e0 = expf(v0 - m), e1 = expf(v1 - m);
    float s = e0 + e1;
    for (int off = 32; off; off >>= 1) s += __shfl_xor(s, off);
    if ((tid & 63) == 0) red[tid >> 6] = s;
    __syncthreads();
    s = red[0] + red[1] + red[2] + red[3];
    float inv = 1.f / s;
    float r0 = e0 * inv, r1 = e1 * inv;
    row[tid] = r0;
    row[tid + 256] = r1;
    if (j < 256) { if (tid == j) diagS[b * 512 + j] = r0; }
    else { if (tid == j - 256) diagS[b * 512 + j] = r1; }
}

// Tx1[b,i,:,:] = sum_edges (csr_w*ST[b][col][i]*diagS[b][col]) * X[b,col,:,:]
__global__ __launch_bounds__(256) void k_prop1(const float* __restrict__ X,
                                               const float* __restrict__ ST,
                                               const float* __restrict__ diagS,
                                               const float* __restrict__ csr_w,
                                               const int* __restrict__ csr_col,
                                               const int* __restrict__ row_start,
                                               float* __restrict__ Tx1) {
    int blk = ((blockIdx.x & 7) << 8) + (blockIdx.x >> 3);   // 2048 % 8 == 0
    int b = blk >> 9, i = blk & 511;
    int tid = threadIdx.x;
    int s = row_start[i], e2 = row_start[i + 1];
    const float4* Xb = (const float4*)(X + (size_t)b * 512 * 1024);
    const float* STb = ST + (size_t)b * 512 * 512;
    const float* dSb = diagS + b * 512;
    float4 acc = make_float4(0.f, 0.f, 0.f, 0.f);
    for (int p = s; p < e2; ++p) {
        int col = csr_col[p];
        float w = csr_w[p] * STb[(size_t)col * 512 + i] * dSb[col];
        float4 v = Xb[col * 256 + tid];
        acc.x += w * v.x; acc.y += w * v.y; acc.z += w * v.z; acc.w += w * v.w;
    }
    *(float4*)(Tx1 + (size_t)blk * 1024 + tid * 4) = acc;
}

// ============ fused prop2 + cheb + time-conv/residual/LN/transpose ============
// one block per (b,i) row. LDS 17.4 KB -> 9 blocks/CU. t0 recomputed inline;
// phase C: thread owns (o, 4 t) and sums over ALL g/f (no cross-wave reduce).
__global__ __launch_bounds__(256) void k_pco(const float* __restrict__ X,
                                             const float* __restrict__ Tx1,
                                             const float* __restrict__ diagS,
                                             const float* __restrict__ csr_w,
                                             const int* __restrict__ csr_col,
                                             const int* __restrict__ row_start,
                                             const float* __restrict__ WcT,
                                             const float* __restrict__ bc,
                                             const float* __restrict__ WtT,
                                             const float* __restrict__ WrT,
                                             const float* __restrict__ bt,
                                             const float* __restrict__ br,
                                             const float* __restrict__ gamma,
                                             const float* __restrict__ beta,
                                             float* __restrict__ out) {
    __shared__ float buf[2048];   // t1s=[0..1023] t2s=[1024..2047]; later z[t*65+o] (1040)
    __shared__ float xl[1024];    // raw X row [f][t]
    __shared__ float xh[1280];    // [g][20], slot=t+1, halo zeros
    int blk = ((blockIdx.x & 7) << 8) + (blockIdx.x >> 3);
    int b = blk >> 9, i = blk & 511;
    int tid = threadIdx.x;
#pragma unroll
    for (int k = 0; k < 5; ++k) xh[tid + 256 * k] = 0.f;
    // --- phase A: prop2 gather (Tx2 row stays in LDS) ---
    int s = row_start[i], e2 = row_start[i + 1];
    const float* T1b = Tx1 + (size_t)b * 512 * 1024 + tid * 4;
    float4 acc = make_float4(0.f, 0.f, 0.f, 0.f);
    for (int p = s; p < e2; ++p) {
        int col = csr_col[p];
        float w = csr_w[p];
        float4 v = *(const float4*)(T1b + (size_t)col * 1024);
        acc.x += w * v.x; acc.y += w * v.y; acc.z += w * v.z; acc.w += w * v.w;
    }
    float ds = diagS[blk];
    size_t roff = (size_t)blk * 1024 + tid * 4;
    float4 x0 = *(const float4*)(X + roff);
    float4 t1v = *(const float4*)(Tx1 + roff);
    float4 t2v;
    t2v.x = 2.f * acc.x - ds * x0.x;
    t2v.y = 2.f * acc.y - ds * x0.y;
    t2v.z = 2.f * acc.z - ds * x0.z;
    t2v.w = 2.f * acc.w - ds * x0.w;
    *(float4*)(buf + tid * 4) = t1v;
    *(float4*)(buf + 1024 + tid * 4) = t2v;
    *(float4*)(xl + tid * 4) = x0;
    __syncthreads();
    // --- phase B: cheb -> xh[g][20]  (t0 = ds*xl inline; WcT float4 weights) ---
    {
        int g = tid >> 2, t4 = (tid & 3) * 4;
        float bcg = bc[g];
        float4 accg = make_float4(bcg, bcg, bcg, bcg);
        const float* t1s = buf;
        const float* t2s = buf + 1024;
        const float* wgp = WcT + g * 192;
        for (int f0 = 0; f0 < 64; f0 += 4) {
            float4 wq0 = *(const float4*)(wgp + f0);
            float4 wq1 = *(const float4*)(wgp + 64 + f0);
            float4 wq2 = *(const float4*)(wgp + 128 + f0);
#pragma unroll
            for (int ff = 0; ff < 4; ++ff) {
                int f = f0 + ff;
                float w0 = ff == 0 ? wq0.x : ff == 1 ? wq0.y : ff == 2 ? wq0.z : wq0.w;
                float w1 = ff == 0 ? wq1.x : ff == 1 ? wq1.y : ff == 2 ? wq1.z : wq1.w;
                float w2 = ff == 0 ? wq2.x : ff == 1 ? wq2.y : ff == 2 ? wq2.z : wq2.w;
                float4 xv = *(const float4*)(xl + f * 16 + t4);
                float4 a1 = *(const float4*)(t1s + f * 16 + t4);
                float4 a2 = *(const float4*)(t2s + f * 16 + t4);
                float a0x = ds * xv.x, a0y = ds * xv.y, a0z = ds * xv.z, a0w = ds * xv.w;
                accg.x += w0 * a0x + w1 * a1.x + w2 * a2.x;
                accg.y += w0 * a0y + w1 * a1.y + w2 * a2.y;
                accg.z += w0 * a0z + w1 * a1.z + w2 * a2.z;
                accg.w += w0 * a0w + w1 * a1.w + w2 * a2.w;
            }
        }
        xh[g * 20 + t4 + 1] = fmaxf(accg.x, 0.f);
        xh[g * 20 + t4 + 2] = fmaxf(accg.y, 0.f);
        xh[g * 20 + t4 + 3] = fmaxf(accg.z, 0.f);
        xh[g * 20 + t4 + 4] = fmaxf(accg.w, 0.f);
    }
    __syncthreads();   // buf (t1s/t2s) free for reuse as z
    // --- phase C: temporal conv + residual + relu + LN + transpose ---
    float* z = buf;
    int o = tid & 63, tg = tid >> 6;
    float accv[4] = {0.f, 0.f, 0.f, 0.f};
    for (int g = 0; g < 64; ++g) {
        float w0 = WtT[(g * 3 + 0) * 64 + o];
        float w1 = WtT[(g * 3 + 1) * 64 + o];
        float w2 = WtT[(g * 3 + 2) * 64 + o];
        const float* xg = xh + g * 20 + tg * 4;
#pragma unroll
        for (int tt = 0; tt < 4; ++tt)
            accv[tt] += xg[tt] * w0 + xg[tt + 1] * w1 + xg[tt + 2] * w2;
    }
    for (int f = 0; f < 64; ++f) {
        float w = WrT[f * 64 + o];
        const float* xf = xl + f * 16 + tg * 4;
#pragma unroll
        for (int tt = 0; tt < 4; ++tt) accv[tt] += xf[tt] * w;
    }
    float bsum = bt[o] + br[o];
    float go = gamma[o], bo = beta[o];
#pragma unroll
    for (int tt = 0; tt < 4; ++tt) {
        int t = tg * 4 + tt;
        float zv = fmaxf(bsum + accv[tt], 0.f);
        float sv = zv, sq = zv * zv;
        for (int off = 32; off; off >>= 1) {
            sv += __shfl_xor(sv, off);
            sq += __shfl_xor(sq, off);
        }
        float mu = sv * (1.f / 64.f);
        float var = sq * (1.f / 64.f) - mu * mu;
        z[t * 65 + o] = (zv - mu) * rsqrtf(var + 1e-5f) * go + bo;
    }
    __syncthreads();
#pragma unroll
    for (int k = 0; k < 4; ++k) {
        int idx = tid + 256 * k;             // idx = o*16 + t
        out[(size_t)blk * 1024 + idx] = z[(idx & 15) * 65 + (idx >> 4)];
    }
}

extern "C" void kernel_launch(void* const* d_in, const int* in_sizes, int n_in,
                              void* d_out, int out_size, void* d_ws, size_t ws_size,
                              hipStream_t stream) {
    const float* X     = (const float*)d_in[0];
    const int*   ei    = (const int*)d_in[1];
    const float* U1    = (const float*)d_in[2];
    const float* U2    = (const float*)d_in[3];
    const float* U3    = (const float*)d_in[4];
    const float* be    = (const float*)d_in[5];
    const float* Ve    = (const float*)d_in[6];
    const float* Ws1   = (const float*)d_in[7];
    const float* Ws2   = (const float*)d_in[8];
    const float* Ws3   = (const float*)d_in[9];
    const float* bs    = (const float*)d_in[10];
    const float* Vs    = (const float*)d_in[11];
    const float* Wc    = (const float*)d_in[12];
    const float* bc    = (const float*)d_in[13];
    const float* Wt    = (const float*)d_in[14];
    const float* bt    = (const float*)d_in[15];
    const float* Wr    = (const float*)d_in[16];
    const float* br    = (const float*)d_in[17];
    const float* gamma = (const float*)d_in[18];
    const float* beta  = (const float*)d_in[19];

    float* ws = (float*)d_ws;
    float* Tx1    = ws + TX1_OFF;
    float* ST     = ws + ST_OFF;     // shares TX1 region (read during prop1 only)
    float* sigT   = ws + SIGT_OFF;
    float* bsT    = ws + BST_OFF;
    float* Et     = ws + ET_OFF;
    float* part   = ws + PART_OFF;
    float* rhs_t  = ws + RHST_OFF;
    float* lhs_s  = ws + LHSS_OFF;
    float* rhs_sn = ws + RHSSN_OFF;
    float* diagS  = ws + DIAGS_OFF;
    float* csr_w  = ws + CSRW_OFF;
    float* WtT    = ws + WTT_OFF;
    float* WrT    = ws + WRT_OFF;
    float* rhs3   = ws + RHS3_OFF;
    float* ew1    = ws + EW1_OFF;
    float* Mpart  = ws + MPART_OFF;
    float* WcT    = ws + WCT_OFF;

    int* ib        = (int*)(ws + FEND);
    int* row_start = ib;                  // 513 (pad to 516)
    int* csr_col   = ib + 516;            // NE
    int* counts    = csr_col + NE;        // 64*512

    // merged prep: hist + weight transposes + temporal-attention inputs
    k_prep<<<400, 256, 0, stream>>>(ei, counts, Wt, Wr, Wc, bs, WtT, WrT, WcT, bsT,
                                    X, U1, U3, Ws3, part, rhs_t, rhs3);
    // fused scan+CSR fill + M partials
    k_graph<<<96, 512, 0, stream>>>(ei, counts, row_start, csr_col, csr_w,
                                    rhs_t, U2, Mpart);

    k_temporal<<<4, 256, 0, stream>>>(part, Mpart, be, Ve, Ws1, Et, ew1);

    // spatial attention (Xt eliminated algebraically)
    k_spat2<<<512, 256, 0, stream>>>(X, ew1, rhs3, Et, Ws2, lhs_s, rhs_sn);
    k_sigT<<<4096, 256, 0, stream>>>(lhs_s, rhs_sn, bsT, sigT);
    k_gemm_s<<<dim3(8, 8, 4), 256, 0, stream>>>(sigT, Vs, ST);
    k_softmax_s<<<2048, 256, 0, stream>>>(ST, diagS);

    // chebyshev conv: prop1 (wS inline) -> fused prop2+cheb+timeconv+LN+transpose
    k_prop1<<<2048, 256, 0, stream>>>(X, ST, diagS, csr_w, csr_col, row_start, Tx1);
    k_pco<<<2048, 256, 0, stream>>>(X, Tx1, diagS, csr_w, csr_col, row_start,
                                    WcT, bc, WtT, WrT, bt, br, gamma, beta,
                                    (float*)d_out);
}

// Round 14
// 145.702 us; speedup vs baseline: 1.0822x; 1.0822x over previous
//
#include <hip/hip_runtime.h>
#include <math.h>

#define NB 4
#define NV 512
#define NF 64
#define NT 16
#define NE 16384

// ---------------- workspace layout (float offsets) ----------------
#define TX1_OFF    2097152u    // 2097152
#define SIGT_OFF   4194304u    // 2097152
#define ST_OFF     6291456u    // 1048576 (own region; no aliasing with Tx1)
#define BST_OFF    8388608u    // bs transposed 262144
#define ET_OFF     8650752u    // (B,16,16) 1024
#define PART_OFF   8651776u    // lhs1 partials 4*8*1024 = 32768
#define RHST_OFF   8684544u    // rhs_t (B,N,T) 32768
#define LHSS_OFF   8717312u    // lhs_s (B,N,T) 32768
#define RHSSN_OFF  8750080u    // rhs_s stored (B,N,T) 32768
#define DIAGS_OFF  8782848u    // (B,N) 2048
#define CSRW_OFF   8850432u    // 16384
#define WTT_OFF    8866816u    // 12288
#define WRT_OFF    8879104u    // 4096
#define RHS3_OFF   8883712u    // rhs3 (B,N,T) 32768
#define EW1_OFF    8916480u    // (B,16) 64
#define MPART_OFF  8916544u    // M partials 4*8*1024 = 32768
#define FEND       8949312u    // floats; ints live after this

// ============ merged prep: hist + bsT + WtT/WrT + lhs1 partials + rhs/rhs3 ============
__global__ void k_prep(const int* __restrict__ ei, int* __restrict__ counts,
                       const float* __restrict__ Wt, const float* __restrict__ Wr,
                       const float* __restrict__ bs,
                       float* __restrict__ WtT, float* __restrict__ WrT,
                       float* __restrict__ bsT,
                       const float* __restrict__ X, const float* __restrict__ U1,
                       const float* __restrict__ U3, const float* __restrict__ Ws3,
                       float* __restrict__ part, float* __restrict__ rhs,
                       float* __restrict__ rhs3) {
    __shared__ int h[512];
    __shared__ float tile[64][65];
    int bid = blockIdx.x, tid = threadIdx.x;
    if (bid < 64) {
        int c = bid;
        h[tid] = 0; h[tid + 256] = 0;
        __syncthreads();
        atomicAdd(&h[ei[c * 256 + tid]], 1);
        __syncthreads();
        counts[c * 512 + tid] = h[tid];
        counts[c * 512 + tid + 256] = h[tid + 256];
    } else if (bid < 128) {
        int tb = bid - 64;
        int r0 = (tb >> 3) * 64, c0 = (tb & 7) * 64;
        int c = tid & 63, rq = tid >> 6;
        for (int k = 0; k < 16; ++k) {
            int r = rq * 16 + k;
            tile[r][c] = bs[(r0 + r) * 512 + c0 + c];
        }
        __syncthreads();
        int r2 = tid & 63;
        for (int k = 0; k < 16; ++k) {
            int c2 = rq * 16 + k;
            bsT[(size_t)(c0 + c2) * 512 + r0 + r2] = tile[r2][c2];
        }
    } else if (bid < 192) {
        int idx = (bid - 128) * 256 + tid;
        if (idx < 12288) {
            int o = idx & 63, gd = idx >> 6;      // gd = g*3+dt
            int g = gd / 3, dt = gd - g * 3;
            WtT[idx] = Wt[(o * 64 + g) * 3 + dt];
        } else {
            int i2 = idx - 12288;
            int o = i2 & 63, f = i2 >> 6;
            WrT[i2] = Wr[o * 64 + f];
        }
    } else {
        int sub = bid - 192;
        if (sub < 32) {
            int b = sub >> 3, g = sub & 7;
            float acc[4] = {0.f, 0.f, 0.f, 0.f};
            const float* Xb = X + (size_t)b * NV * 1024;
            int n0 = g * 64;
            for (int nn = 0; nn < 64; ++nn) {
                int n = n0 + nn;
                float u = U1[n];
                const float* xp = Xb + (size_t)n * 1024;
#pragma unroll
                for (int k = 0; k < 4; ++k) acc[k] += xp[tid + 256 * k] * u;
            }
#pragma unroll
            for (int k = 0; k < 4; ++k) part[(size_t)(b * 8 + g) * 1024 + tid + 256 * k] = acc[k];
        } else {
            int gid = (sub - 32) * 256 + tid;
            int t = gid & 15;
            const float* xp = X + ((size_t)(gid >> 4)) * 1024 + t;
            float a = 0.f, a3 = 0.f;
#pragma unroll
            for (int f = 0; f < 64; ++f) {
                float v = xp[f * 16];
                a += U3[f] * v;
                a3 += Ws3[f] * v;
            }
            rhs[gid] = a;
            rhs3[gid] = a3;
        }
    }
}

// ============ fused: scan+CSR fill (blocks 0..63) + M partials (blocks 64..95) ============
__global__ __launch_bounds__(512) void k_graph(const int* __restrict__ ei,
                                               const int* __restrict__ counts,
                                               int* __restrict__ row_start,
                                               int* __restrict__ csr_col,
                                               float* __restrict__ csr_w,
                                               const float* __restrict__ rhs_g,
                                               const float* __restrict__ U2,
                                               float* __restrict__ Mpart) {
    __shared__ int sc[512];
    __shared__ int base_l[512];
    __shared__ float dis_l[512];
    __shared__ int rs_l[512];
    __shared__ int rowL[256];
    __shared__ float rhsL[1024];
    int bid = blockIdx.x, tid = threadIdx.x;
    if (bid < 64) {
        int c = bid;
        int r = tid;
        int sum = 0, base = 0;
        for (int cc = 0; cc < 64; ++cc) {
            if (cc == c) base = sum;
            sum += counts[cc * 512 + r];
        }
        base_l[r] = base;
        dis_l[r] = sum > 0 ? 1.0f / sqrtf((float)sum) : 0.0f;
        sc[r] = sum;
        __syncthreads();
        for (int off = 1; off < 512; off <<= 1) {
            int v = sc[r];
            int add = (r >= off) ? sc[r - off] : 0;
            __syncthreads();
            sc[r] = v + add;
            __syncthreads();
        }
        rs_l[r] = sc[r] - sum;          // exclusive row start
        if (c == 0) {
            row_start[r] = sc[r] - sum;
            if (r == 511) row_start[512] = sc[r];
        }
        if (tid < 256) rowL[tid] = ei[c * 256 + tid];
        __syncthreads();
        if (tid < 256) {
            int rr = rowL[tid];
            int col = ei[NE + c * 256 + tid];
            int rank = 0;
            for (int j = 0; j < tid; ++j)
                if (rowL[j] == rr) rank++;
            int pos = rs_l[rr] + base_l[rr] + rank;
            csr_col[pos] = col;
            csr_w[pos] = -dis_l[rr] * dis_l[col];
        }
    } else {
        int sub = bid - 64;             // 0..31
        int b = sub >> 3, g = sub & 7;
        rhsL[tid] = rhs_g[(size_t)b * 8192 + g * 1024 + tid];
        rhsL[tid + 512] = rhs_g[(size_t)b * 8192 + g * 1024 + tid + 512];
        __syncthreads();
        float acc[2] = {0.f, 0.f};
        int fA[2], tA[2];
#pragma unroll
        for (int k = 0; k < 2; ++k) { int idx = tid + 512 * k; fA[k] = idx >> 4; tA[k] = idx & 15; }
        int n0 = g * 64;
        for (int nn = 0; nn < 64; ++nn) {
#pragma unroll
            for (int k = 0; k < 2; ++k)
                acc[k] += U2[fA[k] * 512 + n0 + nn] * rhsL[nn * 16 + tA[k]];
        }
#pragma unroll
        for (int k = 0; k < 2; ++k) Mpart[(size_t)(b * 8 + g) * 1024 + tid + 512 * k] = acc[k];
    }
}

__global__ void k_temporal(const float* __restrict__ part, const float* __restrict__ Mpart,
                           const float* __restrict__ be,
                           const float* __restrict__ Ve, const float* __restrict__ Ws1,
                           float* __restrict__ Et, float* __restrict__ ew1) {
    __shared__ float lhs1[1024];
    __shared__ float M[1024];
    __shared__ float Esig[256];
    __shared__ float Et0[256];
    __shared__ float red[32];
    __shared__ float EtL[256];
    int b = blockIdx.x, tid = threadIdx.x;
#pragma unroll
    for (int k = 0; k < 4; ++k) {
        int idx = tid + 256 * k;
        float s = 0.f, m = 0.f;
        for (int g = 0; g < 8; ++g) {
            s += part[(size_t)(b * 8 + g) * 1024 + idx];
            m += Mpart[(size_t)(b * 8 + g) * 1024 + idx];
        }
        lhs1[idx] = s;
        M[idx] = m;
    }
    __syncthreads();
    {
        int t1 = tid >> 4, t2 = tid & 15;
        float s = 0.f;
        for (int f = 0; f < 64; ++f) s += lhs1[f * 16 + t1] * M[f * 16 + t2];
        s += be[t1 * 16 + t2];
        Esig[tid] = 1.f / (1.f + expf(-s));
    }
    __syncthreads();
    {
        int t1 = tid >> 4, t2 = tid & 15;
        float s = 0.f;
        for (int k = 0; k < 16; ++k) s += Ve[t1 * 16 + k] * Esig[k * 16 + t2];
        Et0[tid] = s;
    }
    __syncthreads();
    if (tid < 16) {
        float m = -1e30f;
        for (int k = 0; k < 16; ++k) m = fmaxf(m, Et0[k * 16 + tid]);
        float s = 0.f;
        for (int k = 0; k < 16; ++k) s += expf(Et0[k * 16 + tid] - m);
        red[tid] = m; red[16 + tid] = 1.f / s;
    }
    __syncthreads();
    {
        int t2 = tid & 15;
        float etv = expf(Et0[tid] - red[t2]) * red[16 + t2];
        Et[b * 256 + tid] = etv;
        EtL[tid] = etv;
    }
    __syncthreads();
    if (tid < 16) {
        float s = 0.f;
        for (int t = 0; t < 16; ++t) s += EtL[tid * 16 + t] * Ws1[t];
        ew1[b * 16 + tid] = s;     // ew1[tp] = sum_t Et[tp][t]*Ws1[t]
    }
}

// ============ spatial attention lhs/rhs directly from X (Xt eliminated) ============
__global__ __launch_bounds__(256) void k_spat2(const float* __restrict__ X,
                                               const float* __restrict__ ew1,
                                               const float* __restrict__ rhs3,
                                               const float* __restrict__ Et,
                                               const float* __restrict__ Ws2,
                                               float* __restrict__ lhs_s,
                                               float* __restrict__ rhs_sn) {
    int wv = threadIdx.x >> 6, lane = threadIdx.x & 63;
    int bn = blockIdx.x * 4 + wv;
    int b = bn >> 9;
    const float4* xp = (const float4*)(X + (size_t)bn * 1024 + lane * 16);
    float4 x0 = xp[0], x1 = xp[1], x2 = xp[2], x3 = xp[3];
    const float* e1 = ew1 + b * 16;
    float l1 = x0.x * e1[0] + x0.y * e1[1] + x0.z * e1[2] + x0.w * e1[3]
             + x1.x * e1[4] + x1.y * e1[5] + x1.z * e1[6] + x1.w * e1[7]
             + x2.x * e1[8] + x2.y * e1[9] + x2.z * e1[10] + x2.w * e1[11]
             + x3.x * e1[12] + x3.y * e1[13] + x3.z * e1[14] + x3.w * e1[15];
    const float4* wp = (const float4*)(Ws2 + lane * 16);
    float4 w0 = wp[0], w1 = wp[1], w2 = wp[2], w3 = wp[3];
    float p[16] = {l1 * w0.x, l1 * w0.y, l1 * w0.z, l1 * w0.w,
                   l1 * w1.x, l1 * w1.y, l1 * w1.z, l1 * w1.w,
                   l1 * w2.x, l1 * w2.y, l1 * w2.z, l1 * w2.w,
                   l1 * w3.x, l1 * w3.y, l1 * w3.z, l1 * w3.w};
#pragma unroll
    for (int off = 32; off; off >>= 1) {
#pragma unroll
        for (int k = 0; k < 16; ++k) p[k] += __shfl_xor(p[k], off);
    }
    if (lane == 0) {
        float4* lp = (float4*)(lhs_s + (size_t)bn * 16);
        lp[0] = make_float4(p[0], p[1], p[2], p[3]);
        lp[1] = make_float4(p[4], p[5], p[6], p[7]);
        lp[2] = make_float4(p[8], p[9], p[10], p[11]);
        lp[3] = make_float4(p[12], p[13], p[14], p[15]);
    }
    if (lane < 16) {
        const float* r3 = rhs3 + (size_t)bn * 16;
        const float* Eb = Et + b * 256;
        float s = 0.f;
#pragma unroll
        for (int tp = 0; tp < 16; ++tp) s += r3[tp] * Eb[tp * 16 + lane];
        rhs_sn[(size_t)bn * 16 + lane] = s;
    }
}

// grid: B*N*N/256 = 4096 blocks (b = gid>>18)
__global__ void k_sigT(const float* __restrict__ lhs_s, const float* __restrict__ rhs_sn,
                       const float* __restrict__ bsT, float* __restrict__ sigT) {
    int gid = blockIdx.x * 256 + threadIdx.x;
    int k = gid & 511, j = (gid >> 9) & 511, b = gid >> 18;
    const float4* lp = (const float4*)(lhs_s + (size_t)(b * 512 + k) * 16);
    const float4* rp = (const float4*)(rhs_sn + (size_t)(b * 512 + j) * 16);
    float s = 0.f;
#pragma unroll
    for (int q = 0; q < 4; ++q) {
        float4 a = lp[q], c = rp[q];
        s += a.x * c.x + a.y * c.y + a.z * c.z + a.w * c.w;
    }
    s += bsT[(size_t)j * 512 + k];
    sigT[gid] = 1.f / (1.f + expf(-s));
}

// S0T[b][j][i] = sum_k sigT[b][j][k] * Vs[i][k]
__global__ __launch_bounds__(256) void k_gemm_s(const float* __restrict__ sigT,
                                                const float* __restrict__ Vs,
                                                float* __restrict__ S0T) {
    __shared__ float As[32 * 68];
    __shared__ float Bs[32 * 68];
    int bI = blockIdx.x, bJ = blockIdx.y, b = blockIdx.z;
    int tid = threadIdx.x, tx = tid & 15, ty = tid >> 4;
    float acc[4][4] = {};
    const float* Ab = sigT + ((size_t)b * 512 + bJ * 64) * 512;
    const float* Bb = Vs + (size_t)bI * 64 * 512;
    for (int k0 = 0; k0 < 512; k0 += 32) {
#pragma unroll
        for (int p = 0; p < 2; ++p) {
            int idx = tid + 256 * p;
            int row = idx >> 3, kk = (idx & 7) * 4;
            float4 a = *(const float4*)(Ab + (size_t)row * 512 + k0 + kk);
            As[(kk + 0) * 68 + row] = a.x; As[(kk + 1) * 68 + row] = a.y;
            As[(kk + 2) * 68 + row] = a.z; As[(kk + 3) * 68 + row] = a.w;
            float4 v = *(const float4*)(Bb + (size_t)row * 512 + k0 + kk);
            Bs[(kk + 0) * 68 + row] = v.x; Bs[(kk + 1) * 68 + row] = v.y;
            Bs[(kk + 2) * 68 + row] = v.z; Bs[(kk + 3) * 68 + row] = v.w;
        }
        __syncthreads();
#pragma unroll
        for (int kk = 0; kk < 32; ++kk) {
            float4 a = *(const float4*)(As + kk * 68 + ty * 4);
            float4 bv = *(const float4*)(Bs + kk * 68 + tx * 4);
            acc[0][0] += a.x * bv.x; acc[0][1] += a.x * bv.y; acc[0][2] += a.x * bv.z; acc[0][3] += a.x * bv.w;
            acc[1][0] += a.y * bv.x; acc[1][1] += a.y * bv.y; acc[1][2] += a.y * bv.z; acc[1][3] += a.y * bv.w;
            acc[2][0] += a.z * bv.x; acc[2][1] += a.z * bv.y; acc[2][2] += a.z * bv.z; acc[2][3] += a.z * bv.w;
            acc[3][0] += a.w * bv.x; acc[3][1] += a.w * bv.y; acc[3][2] += a.w * bv.z; acc[3][3] += a.w * bv.w;
        }
        __syncthreads();
    }
    float* Cb = S0T + ((size_t)b * 512 + bJ * 64) * 512 + bI * 64;
#pragma unroll
    for (int y = 0; y < 4; ++y) {
        int j = ty * 4 + y;
        *(float4*)(Cb + (size_t)j * 512 + tx * 4) =
            make_float4(acc[y][0], acc[y][1], acc[y][2], acc[y][3]);
    }
}

// softmax over i (contiguous) in-place; extract diagonal
__global__ void k_softmax_s(float* __restrict__ ST, float* __restrict__ diagS) {
    __shared__ float red[4];
    int bj = blockIdx.x;
    int b = bj >> 9, j = bj & 511;
    float* row = ST + (size_t)bj * 512;
    int tid = threadIdx.x;
    float v0 = row[tid], v1 = row[tid + 256];
    float m = fmaxf(v0, v1);
    for (int off = 32; off; off >>= 1) m = fmaxf(m, __shfl_xor(m, off));
    if ((tid & 63) == 0) red[tid >> 6] = m;
    __syncthreads();
    m = fmaxf(fmaxf(red[0], red[1]), fmaxf(red[2], red[3]));
    __syncthreads();
    float e0 = expf(v0 - m), e1 = expf(v1 - m);
    float s = e0 + e1;
    for (int off = 32; off; off >>= 1) s += __shfl_xor(s, off);
    if ((tid & 63) == 0) red[tid >> 6] = s;
    __syncthreads();
    s = red[0] + red[1] + red[2] + red[3];
    float inv = 1.f / s;
    float r0 = e0 * inv, r1 = e1 * inv;
    row[tid] = r0;
    row[tid + 256] = r1;
    if (j < 256) { if (tid == j) diagS[b * 512 + j] = r0; }
    else { if (tid == j - 256) diagS[b * 512 + j] = r1; }
}

// Tx1[b,i,:,:] = sum_edges (csr_w*ST[b][col][i]*diagS[b][col]) * X[b,col,:,:]
__global__ __launch_bounds__(256) void k_prop1(const float* __restrict__ X,
                                               const float* __restrict__ ST,
                                               const float* __restrict__ diagS,
                                               const float* __restrict__ csr_w,
                                               const int* __restrict__ csr_col,
                                               const int* __restrict__ row_start,
                                               float* __restrict__ Tx1) {
    int blk = ((blockIdx.x & 7) << 8) + (blockIdx.x >> 3);   // 2048 % 8 == 0
    int b = blk >> 9, i = blk & 511;
    int tid = threadIdx.x;
    int s = row_start[i], e2 = row_start[i + 1];
    const float4* Xb = (const float4*)(X + (size_t)b * 512 * 1024);
    const float* STb = ST + (size_t)b * 512 * 512;
    const float* dSb = diagS + b * 512;
    float4 acc = make_float4(0.f, 0.f, 0.f, 0.f);
    for (int p = s; p < e2; ++p) {
        int col = csr_col[p];
        float w = csr_w[p] * STb[(size_t)col * 512 + i] * dSb[col];
        float4 v = Xb[col * 256 + tid];
        acc.x += w * v.x; acc.y += w * v.y; acc.z += w * v.z; acc.w += w * v.w;
    }
    *(float4*)(Tx1 + (size_t)blk * 1024 + tid * 4) = acc;
}

// ============ fused prop2 + cheb + time-conv/residual/LN/transpose ============
// one block per (b,i) row. Tx2 and Xh never touch global. red aliases t-bufs.
__global__ __launch_bounds__(256) void k_pco(const float* __restrict__ X,
                                             const float* __restrict__ Tx1,
                                             const float* __restrict__ diagS,
                                             const float* __restrict__ csr_w,
                                             const int* __restrict__ csr_col,
                                             const int* __restrict__ row_start,
                                             const float* __restrict__ Wc,
                                             const float* __restrict__ bc,
                                             const float* __restrict__ WtT,
                                             const float* __restrict__ WrT,
                                             const float* __restrict__ bt,
                                             const float* __restrict__ br,
                                             const float* __restrict__ gamma,
                                             const float* __restrict__ beta,
                                             float* __restrict__ out) {
    __shared__ float buf[4160];   // t0s=[0..1023] t1s=[1024..2047] t2s=[2048..3071]; later red[0..4159]
    __shared__ float xl[1024];    // raw X row [f][t]
    __shared__ float xh[1280];    // [g][20], slot=t+1, halo zeros
    int blk = ((blockIdx.x & 7) << 8) + (blockIdx.x >> 3);
    int b = blk >> 9, i = blk & 511;
    int tid = threadIdx.x;
#pragma unroll
    for (int k = 0; k < 5; ++k) xh[tid + 256 * k] = 0.f;
    // --- phase A: prop2 gather (Tx2 row stays in LDS) ---
    int s = row_start[i], e2 = row_start[i + 1];
    const float* T1b = Tx1 + (size_t)b * 512 * 1024 + tid * 4;
    float4 acc = make_float4(0.f, 0.f, 0.f, 0.f);
    for (int p = s; p < e2; ++p) {
        int col = csr_col[p];
        float w = csr_w[p];
        float4 v = *(const float4*)(T1b + (size_t)col * 1024);
        acc.x += w * v.x; acc.y += w * v.y; acc.z += w * v.z; acc.w += w * v.w;
    }
    float ds = diagS[blk];
    size_t roff = (size_t)blk * 1024 + tid * 4;
    float4 x0 = *(const float4*)(X + roff);
    float4 t1v = *(const float4*)(Tx1 + roff);
    float4 t0v, t2v;
    t2v.x = 2.f * acc.x - ds * x0.x;
    t2v.y = 2.f * acc.y - ds * x0.y;
    t2v.z = 2.f * acc.z - ds * x0.z;
    t2v.w = 2.f * acc.w - ds * x0.w;
    t0v.x = x0.x * ds; t0v.y = x0.y * ds; t0v.z = x0.z * ds; t0v.w = x0.w * ds;
    *(float4*)(buf + tid * 4) = t0v;
    *(float4*)(buf + 1024 + tid * 4) = t1v;
    *(float4*)(buf + 2048 + tid * 4) = t2v;
    *(float4*)(xl + tid * 4) = x0;
    __syncthreads();
    // --- phase B: cheb -> xh[g][20] ---
    {
        int g = tid >> 2, t4 = (tid & 3) * 4;
        float bcg = bc[g];
        float4 accg = make_float4(bcg, bcg, bcg, bcg);
        const float* t0s = buf;
        const float* t1s = buf + 1024;
        const float* t2s = buf + 2048;
        for (int f = 0; f < 64; ++f) {
            float w0 = Wc[f * 64 + g];
            float w1 = Wc[4096 + f * 64 + g];
            float w2 = Wc[8192 + f * 64 + g];
            float4 a0 = *(const float4*)(t0s + f * 16 + t4);
            float4 a1 = *(const float4*)(t1s + f * 16 + t4);
            float4 a2 = *(const float4*)(t2s + f * 16 + t4);
            accg.x += w0 * a0.x + w1 * a1.x + w2 * a2.x;
            accg.y += w0 * a0.y + w1 * a1.y + w2 * a2.y;
            accg.z += w0 * a0.z + w1 * a1.z + w2 * a2.z;
            accg.w += w0 * a0.w + w1 * a1.w + w2 * a2.w;
        }
        xh[g * 20 + t4 + 1] = fmaxf(accg.x, 0.f);
        xh[g * 20 + t4 + 2] = fmaxf(accg.y, 0.f);
        xh[g * 20 + t4 + 3] = fmaxf(accg.z, 0.f);
        xh[g * 20 + t4 + 4] = fmaxf(accg.w, 0.f);
    }
    __syncthreads();   // buf free for reuse as red
    // --- phase C: temporal conv + residual + relu + LN + transpose ---
    float* red = buf;
    int o = tid & 63, q = tid >> 6;
    float accv[16];
#pragma unroll
    for (int k = 0; k < 16; ++k) accv[k] = 0.f;
    for (int gi = 0; gi < 16; ++gi) {
        int g = q * 16 + gi;
        const float4* xp = (const float4*)(xh + g * 20);
        float4 xa = xp[0], xb = xp[1], xc = xp[2], xd = xp[3], xe = xp[4];
        float xs[20] = {xa.x, xa.y, xa.z, xa.w, xb.x, xb.y, xb.z, xb.w,
                        xc.x, xc.y, xc.z, xc.w, xd.x, xd.y, xd.z, xd.w,
                        xe.x, xe.y, xe.z, xe.w};
        float w0 = WtT[(g * 3 + 0) * 64 + o];
        float w1 = WtT[(g * 3 + 1) * 64 + o];
        float w2 = WtT[(g * 3 + 2) * 64 + o];
#pragma unroll
        for (int tt = 0; tt < 16; ++tt)
            accv[tt] += xs[tt] * w0 + xs[tt + 1] * w1 + xs[tt + 2] * w2;
    }
    for (int fi = 0; fi < 16; ++fi) {
        int f = q * 16 + fi;
        const float4* xp = (const float4*)(xl + f * 16);
        float4 xa = xp[0], xb = xp[1], xc = xp[2], xd = xp[3];
        float xs[16] = {xa.x, xa.y, xa.z, xa.w, xb.x, xb.y, xb.z, xb.w,
                        xc.x, xc.y, xc.z, xc.w, xd.x, xd.y, xd.z, xd.w};
        float w = WrT[f * 64 + o];
#pragma unroll
        for (int tt = 0; tt < 16; ++tt) accv[tt] += xs[tt] * w;
    }
#pragma unroll
    for (int tt = 0; tt < 16; ++tt) red[q * 1024 + tt * 64 + o] = accv[tt];
    __syncthreads();
    float bsum = bt[o] + br[o];
    float go = gamma[o], bo = beta[o];
    float zv4[4];
#pragma unroll
    for (int tt = 0; tt < 4; ++tt) {
        int t = q * 4 + tt;
        float sv = bsum;
#pragma unroll
        for (int qq = 0; qq < 4; ++qq) sv += red[qq * 1024 + t * 64 + o];
        zv4[tt] = fmaxf(sv, 0.f);
    }
    __syncthreads();    // before reusing red as z
#pragma unroll
    for (int tt = 0; tt < 4; ++tt) {
        int t = q * 4 + tt;
        float zv = zv4[tt];
        float sv = zv, sq = zv * zv;
        for (int off = 32; off; off >>= 1) {
            sv += __shfl_xor(sv, off);
            sq += __shfl_xor(sq, off);
        }
        float mu = sv * (1.f / 64.f);
        float var = sq * (1.f / 64.f) - mu * mu;
        red[t * 65 + o] = (zv - mu) * rsqrtf(var + 1e-5f) * go + bo;
    }
    __syncthreads();
#pragma unroll
    for (int k = 0; k < 4; ++k) {
        int idx = tid + 256 * k;             // idx = o*16 + t
        out[(size_t)blk * 1024 + idx] = red[(idx & 15) * 65 + (idx >> 4)];
    }
}

extern "C" void kernel_launch(void* const* d_in, const int* in_sizes, int n_in,
                              void* d_out, int out_size, void* d_ws, size_t ws_size,
                              hipStream_t stream) {
    const float* X     = (const float*)d_in[0];
    const int*   ei    = (const int*)d_in[1];
    const float* U1    = (const float*)d_in[2];
    const float* U2    = (const float*)d_in[3];
    const float* U3    = (const float*)d_in[4];
    const float* be    = (const float*)d_in[5];
    const float* Ve    = (const float*)d_in[6];
    const float* Ws1   = (const float*)d_in[7];
    const float* Ws2   = (const float*)d_in[8];
    const float* Ws3   = (const float*)d_in[9];
    const float* bs    = (const float*)d_in[10];
    const float* Vs    = (const float*)d_in[11];
    const float* Wc    = (const float*)d_in[12];
    const float* bc    = (const float*)d_in[13];
    const float* Wt    = (const float*)d_in[14];
    const float* bt    = (const float*)d_in[15];
    const float* Wr    = (const float*)d_in[16];
    const float* br    = (const float*)d_in[17];
    const float* gamma = (const float*)d_in[18];
    const float* beta  = (const float*)d_in[19];

    float* ws = (float*)d_ws;
    float* Tx1    = ws + TX1_OFF;
    float* ST     = ws + ST_OFF;     // dedicated region (no Tx1 aliasing)
    float* sigT   = ws + SIGT_OFF;
    float* bsT    = ws + BST_OFF;
    float* Et     = ws + ET_OFF;
    float* part   = ws + PART_OFF;
    float* rhs_t  = ws + RHST_OFF;
    float* lhs_s  = ws + LHSS_OFF;
    float* rhs_sn = ws + RHSSN_OFF;
    float* diagS  = ws + DIAGS_OFF;
    float* csr_w  = ws + CSRW_OFF;
    float* WtT    = ws + WTT_OFF;
    float* WrT    = ws + WRT_OFF;
    float* rhs3   = ws + RHS3_OFF;
    float* ew1    = ws + EW1_OFF;
    float* Mpart  = ws + MPART_OFF;

    int* ib        = (int*)(ws + FEND);
    int* row_start = ib;                  // 513 (pad to 516)
    int* csr_col   = ib + 516;            // NE
    int* counts    = csr_col + NE;        // 64*512

    // merged prep: hist + weight transposes + temporal-attention inputs
    k_prep<<<352, 256, 0, stream>>>(ei, counts, Wt, Wr, bs, WtT, WrT, bsT,
                                    X, U1, U3, Ws3, part, rhs_t, rhs3);
    // fused scan+CSR fill + M partials
    k_graph<<<96, 512, 0, stream>>>(ei, counts, row_start, csr_col, csr_w,
                                    rhs_t, U2, Mpart);

    k_temporal<<<4, 256, 0, stream>>>(part, Mpart, be, Ve, Ws1, Et, ew1);

    // spatial attention (Xt eliminated algebraically)
    k_spat2<<<512, 256, 0, stream>>>(X, ew1, rhs3, Et, Ws2, lhs_s, rhs_sn);
    k_sigT<<<4096, 256, 0, stream>>>(lhs_s, rhs_sn, bsT, sigT);
    k_gemm_s<<<dim3(8, 8, 4), 256, 0, stream>>>(sigT, Vs, ST);
    k_softmax_s<<<2048, 256, 0, stream>>>(ST, diagS);

    // chebyshev conv: prop1 (wS inline) -> fused prop2+cheb+timeconv+LN+transpose
    k_prop1<<<2048, 256, 0, stream>>>(X, ST, diagS, csr_w, csr_col, row_start, Tx1);
    k_pco<<<2048, 256, 0, stream>>>(X, Tx1, diagS, csr_w, csr_col, row_start,
                                    Wc, bc, WtT, WrT, bt, br, gamma, beta,
                                    (float*)d_out);
}